// Round 2
// baseline (2402.814 us; speedup 1.0000x reference)
//
#include <hip/hip_runtime.h>

// GraphEncoder: 3x ChebConv(K=6) + GroupNorm(8)/ReLU + dense readout.
// Strategy:
//  - Build CSR (by row) once per call: histogram -> scan -> scatter, w=-dis[r]*dis[c].
//  - Layers 1/2: prop and @W commute => out = sum_j L^j (X @ C_j), C_j = sum_k a[k][j] W_k
//    (monomial expansion of Chebyshev). One GEMM X@[C0..C5] -> Y slices, then Horner:
//    H=Y5; for j=4..0: H = L*H + Y_j  (in-place on Y slices, prop in cout space).
//  - Layer 0 (cin=3): classic Chebyshev recursion on 3 channels, TxAll (N x 24, zero pad),
//    one K=24 GEMM.
//  - GroupNorm+bias+ReLU fused per (node,group) thread.
//  - Readout: (16 x 320000) @ (320000 x 128): chunked split-K, h3 chunk in LDS, atomicAdd.
// R1 fix: edge_index is staged by the harness as int32 (ALL integer inputs -> const int*).
//         Reading it as int64 produced garbage indices -> OOB atomics -> HSA abort.

#define NN 160000
#define EE 2560000
#define FDC 640

// ----------------- CSR build -----------------
__global__ __launch_bounds__(256) void k_zero(int* __restrict__ p, int n) {
  int i = blockIdx.x * 256 + threadIdx.x;
  if (i < n) p[i] = 0;
}

__global__ __launch_bounds__(256) void k_hist(const int* __restrict__ ei, int* __restrict__ deg) {
  int e = blockIdx.x * 256 + threadIdx.x;
  if (e < EE) atomicAdd(&deg[ei[e]], 1);
}

__global__ __launch_bounds__(256) void k_dis(const int* __restrict__ deg, float* __restrict__ dis) {
  int i = blockIdx.x * 256 + threadIdx.x;
  if (i < NN) { int d = deg[i]; dis[i] = d > 0 ? rsqrtf((float)d) : 0.f; }
}

__global__ __launch_bounds__(256) void k_scan1(const int* __restrict__ deg, int* __restrict__ rowStart,
                                               int* __restrict__ bsum) {
  __shared__ int s[256];
  int tid = threadIdx.x;
  int i = blockIdx.x * 256 + tid;        // grid exact: 625*256 = NN
  int v = deg[i];
  s[tid] = v;
  __syncthreads();
  for (int off = 1; off < 256; off <<= 1) {
    int t = (tid >= off) ? s[tid - off] : 0;
    __syncthreads();
    s[tid] += t;
    __syncthreads();
  }
  rowStart[i] = s[tid] - v;              // block-local exclusive
  if (tid == 255) bsum[blockIdx.x] = s[255];
}

__global__ void k_scan2(int* __restrict__ bsum, int nb) {
  __shared__ int s[1024];
  int tid = threadIdx.x;
  int v = (tid < nb) ? bsum[tid] : 0;
  s[tid] = v;
  __syncthreads();
  for (int off = 1; off < 1024; off <<= 1) {
    int t = (tid >= off) ? s[tid - off] : 0;
    __syncthreads();
    s[tid] += t;
    __syncthreads();
  }
  if (tid < nb) bsum[tid] = s[tid] - v;  // exclusive block offsets
}

__global__ __launch_bounds__(256) void k_scan3(int* __restrict__ rowStart, const int* __restrict__ bsum) {
  int i = blockIdx.x * 256 + threadIdx.x;
  rowStart[i] += bsum[blockIdx.x];
  if (i == 0) rowStart[NN] = EE;
}

__global__ __launch_bounds__(256) void k_scatter(const int* __restrict__ ei, const int* __restrict__ rowStart,
                                                 int* __restrict__ cursor, const float* __restrict__ dis,
                                                 int* __restrict__ colIdx, float* __restrict__ wE) {
  int e = blockIdx.x * 256 + threadIdx.x;
  if (e >= EE) return;
  int r = ei[e];
  int c = ei[EE + e];
  int pos = rowStart[r] + atomicAdd(&cursor[r], 1);
  colIdx[pos] = c;
  wE[pos] = -dis[r] * dis[c];
}

// ----------------- Layer 0 (cin=3) classic Chebyshev -----------------
__global__ __launch_bounds__(256) void k_copyx(const float* __restrict__ x, float* __restrict__ A,
                                               float* __restrict__ TxAll) {
  int i = blockIdx.x * 256 + threadIdx.x;     // over NN*3
  if (i < NN * 3) {
    float v = x[i];
    A[i] = v;
    int node = i / 3, c = i - node * 3;
    TxAll[node * 24 + c] = v;
  }
}

template <int MODE>   // 1: Tx1 = prop(Tx0); 2: Tnew = 2*prop(Tsrc) - Tdst (in place)
__global__ __launch_bounds__(256) void k_prop3(const float* __restrict__ Tsrc, float* __restrict__ Tdst,
                                               float* __restrict__ TxAll, int ks,
                                               const int* __restrict__ rowStart, const int* __restrict__ colIdx,
                                               const float* __restrict__ wE) {
  int i = blockIdx.x * 256 + threadIdx.x;
  if (i >= NN) return;
  float a0 = 0.f, a1 = 0.f, a2 = 0.f;
  int e = rowStart[i], e1 = rowStart[i + 1];
  for (; e + 1 < e1; e += 2) {
    int c0 = colIdx[e], c1 = colIdx[e + 1];
    float w0 = wE[e], w1 = wE[e + 1];
    float t00 = Tsrc[c0 * 3], t01 = Tsrc[c0 * 3 + 1], t02 = Tsrc[c0 * 3 + 2];
    float t10 = Tsrc[c1 * 3], t11 = Tsrc[c1 * 3 + 1], t12 = Tsrc[c1 * 3 + 2];
    a0 += w0 * t00 + w1 * t10;
    a1 += w0 * t01 + w1 * t11;
    a2 += w0 * t02 + w1 * t12;
  }
  if (e < e1) {
    int c0 = colIdx[e]; float w0 = wE[e];
    a0 += w0 * Tsrc[c0 * 3];
    a1 += w0 * Tsrc[c0 * 3 + 1];
    a2 += w0 * Tsrc[c0 * 3 + 2];
  }
  if (MODE == 2) {
    a0 = 2.f * a0 - Tdst[i * 3];
    a1 = 2.f * a1 - Tdst[i * 3 + 1];
    a2 = 2.f * a2 - Tdst[i * 3 + 2];
  }
  Tdst[i * 3] = a0; Tdst[i * 3 + 1] = a1; Tdst[i * 3 + 2] = a2;
  float* tp = TxAll + i * 24 + ks * 3;
  tp[0] = a0; tp[1] = a1; tp[2] = a2;
}

__global__ __launch_bounds__(256) void k_padW0(const float* __restrict__ W0, float* __restrict__ Cw) {
  int idx = blockIdx.x * 256 + threadIdx.x;   // 24*128
  if (idx < 24 * 128) Cw[idx] = (idx < 18 * 128) ? W0[idx] : 0.f;
}

// ----------------- Monomial coefficient combine: C_j = sum_k a[k][j] W_k -----------------
template <int CIN, int COUT>
__global__ __launch_bounds__(256) void k_combine(const float* __restrict__ W, float* __restrict__ Cw) {
  int idx = blockIdx.x * 256 + threadIdx.x;
  if (idx >= CIN * 6 * COUT) return;
  int co = idx % COUT;
  int j  = (idx / COUT) % 6;
  int ci = idx / (6 * COUT);
  // Chebyshev monomial coefficients a[k][j]; column j extracted:
  float c0, c1, c2, c3, c4, c5;
  switch (j) {
    case 0:  c0 = 1;  c1 = 0;  c2 = -1; c3 = 0;   c4 = 1;  c5 = 0;   break;
    case 1:  c0 = 0;  c1 = 1;  c2 = 0;  c3 = -3;  c4 = 0;  c5 = 5;   break;
    case 2:  c0 = 0;  c1 = 0;  c2 = 2;  c3 = 0;   c4 = -8; c5 = 0;   break;
    case 3:  c0 = 0;  c1 = 0;  c2 = 0;  c3 = 4;   c4 = 0;  c5 = -20; break;
    case 4:  c0 = 0;  c1 = 0;  c2 = 0;  c3 = 0;   c4 = 8;  c5 = 0;   break;
    default: c0 = 0;  c1 = 0;  c2 = 0;  c3 = 0;   c4 = 0;  c5 = 16;  break;
  }
  float s = 0.f;
  s += c0 * W[(0 * CIN + ci) * COUT + co];
  s += c1 * W[(1 * CIN + ci) * COUT + co];
  s += c2 * W[(2 * CIN + ci) * COUT + co];
  s += c3 * W[(3 * CIN + ci) * COUT + co];
  s += c4 * W[(4 * CIN + ci) * COUT + co];
  s += c5 * W[(5 * CIN + ci) * COUT + co];
  Cw[ci * (6 * COUT) + j * COUT + co] = s;
}

// ----------------- Tiled fp32 GEMM: (N x KDIM) @ (KDIM x ncol) -> Y slices -----------------
template <int KDIM, int COUT>
__global__ __launch_bounds__(256) void k_gemm(const float* __restrict__ A, const float* __restrict__ Bm,
                                              int ncol, float* __restrict__ Y) {
  constexpr int KC = (KDIM < 64) ? KDIM : 64;
  __shared__ float As[64 * (KC + 4)];
  __shared__ float Bs[KC * 64];
  int i0 = blockIdx.x * 64;
  int c0 = blockIdx.y * 64;
  float acc[4][4];
#pragma unroll
  for (int ii = 0; ii < 4; ii++)
#pragma unroll
    for (int jj = 0; jj < 4; jj++) acc[ii][jj] = 0.f;
  int tx = threadIdx.x & 15, ty = threadIdx.x >> 4;
  for (int k0 = 0; k0 < KDIM; k0 += KC) {
    if (k0) __syncthreads();
    for (int idx = threadIdx.x; idx < 64 * (KC / 4); idx += 256) {
      int node = idx / (KC / 4), kq = idx % (KC / 4);
      float4 v = *reinterpret_cast<const float4*>(&A[(size_t)(i0 + node) * KDIM + k0 + kq * 4]);
      *reinterpret_cast<float4*>(&As[node * (KC + 4) + kq * 4]) = v;
    }
    for (int idx = threadIdx.x; idx < KC * 16; idx += 256) {
      int kk = idx / 16, cq = idx % 16;
      float4 v = *reinterpret_cast<const float4*>(&Bm[(k0 + kk) * ncol + c0 + cq * 4]);
      *reinterpret_cast<float4*>(&Bs[kk * 64 + cq * 4]) = v;
    }
    __syncthreads();
    for (int k4 = 0; k4 < KC / 4; k4++) {
      float av[4][4], bv[4][4];
#pragma unroll
      for (int ii = 0; ii < 4; ii++) {
        float4 fa = *reinterpret_cast<const float4*>(&As[(ty * 4 + ii) * (KC + 4) + k4 * 4]);
        av[ii][0] = fa.x; av[ii][1] = fa.y; av[ii][2] = fa.z; av[ii][3] = fa.w;
      }
#pragma unroll
      for (int q = 0; q < 4; q++) {
        float4 fb = *reinterpret_cast<const float4*>(&Bs[(k4 * 4 + q) * 64 + tx * 4]);
        bv[q][0] = fb.x; bv[q][1] = fb.y; bv[q][2] = fb.z; bv[q][3] = fb.w;
      }
#pragma unroll
      for (int ii = 0; ii < 4; ii++)
#pragma unroll
        for (int q = 0; q < 4; q++)
#pragma unroll
          for (int jj = 0; jj < 4; jj++) acc[ii][jj] += av[ii][q] * bv[q][jj];
    }
  }
  int jcb = c0 + tx * 4;
  int slice = jcb / COUT;
  int cc = jcb - slice * COUT;
#pragma unroll
  for (int ii = 0; ii < 4; ii++) {
    int i = i0 + ty * 4 + ii;
    float4 o;
    o.x = acc[ii][0]; o.y = acc[ii][1]; o.z = acc[ii][2]; o.w = acc[ii][3];
    *reinterpret_cast<float4*>(&Y[((size_t)slice * NN + i) * COUT + cc]) = o;
  }
}

// ----------------- Horner prop step: Ydst[i] += sum_e w*Ysrc[col]  (in cout space) ---------
template <int C>   // 64 or 32
__global__ __launch_bounds__(256) void k_horner(const float* __restrict__ Ysrc, float* __restrict__ Ydst,
                                                const int* __restrict__ rowStart, const int* __restrict__ colIdx,
                                                const float* __restrict__ wE) {
  int gtid = blockIdx.x * 256 + threadIdx.x;
  int lane = gtid & 63;
  int wave = gtid >> 6;
  int i = wave * (64 / C) + lane / C;
  int ch = lane & (C - 1);
  if (i >= NN) return;
  float acc = Ydst[(size_t)i * C + ch];
  int e = rowStart[i], e1 = rowStart[i + 1];
  for (; e + 1 < e1; e += 2) {
    int c0 = colIdx[e], c1 = colIdx[e + 1];
    float w0 = wE[e], w1 = wE[e + 1];
    acc += w0 * Ysrc[(size_t)c0 * C + ch] + w1 * Ysrc[(size_t)c1 * C + ch];
  }
  if (e < e1) acc += wE[e] * Ysrc[(size_t)colIdx[e] * C + ch];
  Ydst[(size_t)i * C + ch] = acc;
}

// ----------------- GroupNorm(8) + bias + ReLU -----------------
template <int CPG>
__global__ __launch_bounds__(256) void k_gn(const float* __restrict__ src, const float* __restrict__ bias,
                                            const float* __restrict__ gamma, const float* __restrict__ beta,
                                            float* __restrict__ dst) {
  constexpr int C = CPG * 8;
  int t = blockIdx.x * 256 + threadIdx.x;   // (node, group)
  int i = t >> 3, g = t & 7;
  if (i >= NN) return;
  float v[CPG];
  const float4* p4 = reinterpret_cast<const float4*>(src + (size_t)i * C + g * CPG);
#pragma unroll
  for (int q = 0; q < CPG / 4; q++) {
    float4 f = p4[q];
    v[q * 4] = f.x; v[q * 4 + 1] = f.y; v[q * 4 + 2] = f.z; v[q * 4 + 3] = f.w;
  }
  float mean = 0.f;
#pragma unroll
  for (int c = 0; c < CPG; c++) { v[c] += bias[g * CPG + c]; mean += v[c]; }
  mean *= (1.f / CPG);
  float var = 0.f;
#pragma unroll
  for (int c = 0; c < CPG; c++) { float d = v[c] - mean; var += d * d; }
  var *= (1.f / CPG);
  float rs = rsqrtf(var + 1e-5f);
  float* dp = dst + (size_t)i * C + g * CPG;
#pragma unroll
  for (int c = 0; c < CPG; c++) {
    float o = (v[c] - mean) * rs * gamma[g * CPG + c] + beta[g * CPG + c];
    dp[c] = fmaxf(o, 0.f);
  }
}

// ----------------- Readout: (16 x 320000) @ (320000 x 128), split-K + atomics -------------
__global__ __launch_bounds__(256) void k_initout(const float* __restrict__ bl, float* __restrict__ out) {
  int t = blockIdx.x * 256 + threadIdx.x;
  if (t < 2048) out[t] = bl[t & 127];
}

__global__ __launch_bounds__(256) void k_final(const float* __restrict__ h3, const float* __restrict__ Wl,
                                               float* __restrict__ out) {
  __shared__ float hs[16 * FDC];
  int d0 = blockIdx.x * FDC;
  for (int idx = threadIdx.x; idx < 16 * (FDC / 4); idx += 256) {
    int b = idx / (FDC / 4), dq = idx % (FDC / 4);
    float4 v = *reinterpret_cast<const float4*>(&h3[(size_t)b * 320000 + d0 + dq * 4]);
    *reinterpret_cast<float4*>(&hs[b * FDC + dq * 4]) = v;
  }
  __syncthreads();
  int w = threadIdx.x >> 6, lane = threadIdx.x & 63;
  int bh = w & 1, ds = w >> 1;
  float acc0[8], acc1[8];
#pragma unroll
  for (int bb = 0; bb < 8; bb++) { acc0[bb] = 0.f; acc1[bb] = 0.f; }
  for (int dd = ds; dd < FDC; dd += 2) {
    float w0 = Wl[(d0 + dd) * 128 + lane];
    float w1 = Wl[(d0 + dd) * 128 + lane + 64];
#pragma unroll
    for (int bb = 0; bb < 8; bb++) {
      float h = hs[(bh * 8 + bb) * FDC + dd];
      acc0[bb] += w0 * h;
      acc1[bb] += w1 * h;
    }
  }
#pragma unroll
  for (int bb = 0; bb < 8; bb++) {
    atomicAdd(&out[(bh * 8 + bb) * 128 + lane], acc0[bb]);
    atomicAdd(&out[(bh * 8 + bb) * 128 + lane + 64], acc1[bb]);
  }
}

// ----------------- launcher -----------------
extern "C" void kernel_launch(void* const* d_in, const int* in_sizes, int n_in,
                              void* d_out, int out_size, void* d_ws, size_t ws_size,
                              hipStream_t stream) {
  const float* x   = (const float*)d_in[0];
  const int*   ei  = (const int*)d_in[1];   // harness stages ALL integer inputs as int32
  const float* W0  = (const float*)d_in[2];
  const float* b0  = (const float*)d_in[3];
  const float* g0  = (const float*)d_in[4];
  const float* be0 = (const float*)d_in[5];
  const float* W1  = (const float*)d_in[6];
  const float* b1  = (const float*)d_in[7];
  const float* g1  = (const float*)d_in[8];
  const float* be1 = (const float*)d_in[9];
  const float* W2  = (const float*)d_in[10];
  const float* b2  = (const float*)d_in[11];
  const float* g2  = (const float*)d_in[12];
  const float* be2 = (const float*)d_in[13];
  const float* Wl  = (const float*)d_in[14];
  const float* bl  = (const float*)d_in[15];
  float* out = (float*)d_out;
  (void)in_sizes; (void)n_in; (void)out_size; (void)ws_size;

  char* pw = (char*)d_ws;
  auto carve = [&](size_t bytes) -> void* {
    void* r = (void*)pw;
    pw += (bytes + 255) & ~(size_t)255;
    return r;
  };
  int*   deg      = (int*)  carve((size_t)NN * 4);
  int*   cursor   = (int*)  carve((size_t)NN * 4);
  int*   rowStart = (int*)  carve((size_t)(NN + 1) * 4);
  int*   bsum     = (int*)  carve(1024 * 4);
  float* dis      = (float*)carve((size_t)NN * 4);
  int*   colIdx   = (int*)  carve((size_t)EE * 4);
  float* wE       = (float*)carve((size_t)EE * 4);
  float* Cw       = (float*)carve((size_t)6 * 128 * 64 * 4);
  float* TxAll    = (float*)carve((size_t)NN * 24 * 4);
  float* bufHin   = (float*)carve((size_t)NN * 128 * 4);
  float* bufY     = (float*)carve((size_t)NN * 384 * 4);

  // ---- CSR build ----
  k_zero<<<625, 256, 0, stream>>>(deg, NN);
  k_zero<<<625, 256, 0, stream>>>(cursor, NN);
  k_hist<<<10000, 256, 0, stream>>>(ei, deg);
  k_dis<<<625, 256, 0, stream>>>(deg, dis);
  k_scan1<<<625, 256, 0, stream>>>(deg, rowStart, bsum);
  k_scan2<<<1, 1024, 0, stream>>>(bsum, 625);
  k_scan3<<<625, 256, 0, stream>>>(rowStart, bsum);
  k_scatter<<<10000, 256, 0, stream>>>(ei, rowStart, cursor, dis, colIdx, wE);

  // ---- Layer 0 (3 -> 128): classic Chebyshev in cin space ----
  k_zero<<<15000, 256, 0, stream>>>((int*)TxAll, NN * 24);
  float* A3 = bufY;
  float* B3 = bufY + (size_t)NN * 3;
  k_copyx<<<1875, 256, 0, stream>>>(x, A3, TxAll);
  k_prop3<1><<<625, 256, 0, stream>>>(A3, B3, TxAll, 1, rowStart, colIdx, wE);
  k_prop3<2><<<625, 256, 0, stream>>>(B3, A3, TxAll, 2, rowStart, colIdx, wE);
  k_prop3<2><<<625, 256, 0, stream>>>(A3, B3, TxAll, 3, rowStart, colIdx, wE);
  k_prop3<2><<<625, 256, 0, stream>>>(B3, A3, TxAll, 4, rowStart, colIdx, wE);
  k_prop3<2><<<625, 256, 0, stream>>>(A3, B3, TxAll, 5, rowStart, colIdx, wE);
  k_padW0<<<12, 256, 0, stream>>>(W0, Cw);
  k_gemm<24, 128><<<dim3(2500, 2), 256, 0, stream>>>(TxAll, Cw, 128, bufY);
  k_gn<16><<<5000, 256, 0, stream>>>(bufY, b0, g0, be0, bufHin);

  // ---- Layer 1 (128 -> 64): one GEMM + Horner props in cout space ----
  k_combine<128, 64><<<192, 256, 0, stream>>>(W1, Cw);
  k_gemm<128, 64><<<dim3(2500, 6), 256, 0, stream>>>(bufHin, Cw, 384, bufY);
  for (int j = 4; j >= 0; j--)
    k_horner<64><<<40000, 256, 0, stream>>>(bufY + (size_t)(j + 1) * NN * 64,
                                            bufY + (size_t)j * NN * 64, rowStart, colIdx, wE);
  k_gn<8><<<5000, 256, 0, stream>>>(bufY, b1, g1, be1, bufHin);

  // ---- Layer 2 (64 -> 32) ----
  k_combine<64, 32><<<48, 256, 0, stream>>>(W2, Cw);
  k_gemm<64, 32><<<dim3(2500, 3), 256, 0, stream>>>(bufHin, Cw, 192, bufY);
  for (int j = 4; j >= 0; j--)
    k_horner<32><<<20000, 256, 0, stream>>>(bufY + (size_t)(j + 1) * NN * 32,
                                            bufY + (size_t)j * NN * 32, rowStart, colIdx, wE);
  k_gn<4><<<5000, 256, 0, stream>>>(bufY, b2, g2, be2, bufHin);

  // ---- Readout ----
  k_initout<<<8, 256, 0, stream>>>(bl, out);
  k_final<<<500, 256, 0, stream>>>(bufHin, Wl, out);
}

// Round 4
// 1486.189 us; speedup vs baseline: 1.6168x; 1.6168x over previous
//
#include <hip/hip_runtime.h>
#include <hip/hip_fp16.h>

// GraphEncoder: 3x ChebConv(K=6) + GroupNorm(8)/ReLU + dense readout.
// R4: fp16 intermediates (bf16's 7-bit mantissa overshot the error threshold:
//     absmax 4.7e-2 vs 3.39e-2; fp16 is 8x lower rounding noise, same bytes,
//     same MFMA rate). All accumulation fp32.
//  - MFMA f16 GEMMs (16x16x32), B pre-transposed at combine time -> both frags
//    are contiguous-K ds_read_b128 from LDS (pitch +8 ushorts).
//  - Horner prop slices in fp16: 128 B/edge gather, fp16x2 per lane,
//    fp32 accumulate, 4-edge unroll.
//  - Edge (col,w) fused into int2 pairs -> single dwordx2 per edge.

#define NN 160000
#define EE 2560000
#define FDC 640

typedef __attribute__((ext_vector_type(8))) _Float16 half8;
typedef __attribute__((ext_vector_type(4))) float floatx4;

__device__ inline float2 h2f2(unsigned u) {
  __half2 h = __builtin_bit_cast(__half2, u);
  return __half22float2(h);
}
__device__ inline unsigned short f2h(float f) {
  return __builtin_bit_cast(unsigned short, __float2half_rn(f));
}
__device__ inline unsigned packh2(float a, float b) {
  return __builtin_bit_cast(unsigned, __floats2half2_rn(a, b));
}

// ----------------- CSR build -----------------
__global__ __launch_bounds__(256) void k_zero(int* __restrict__ p, int n) {
  int i = blockIdx.x * 256 + threadIdx.x;
  if (i < n) p[i] = 0;
}

__global__ __launch_bounds__(256) void k_hist(const int* __restrict__ ei, int* __restrict__ deg) {
  int e = blockIdx.x * 256 + threadIdx.x;
  if (e < EE) atomicAdd(&deg[ei[e]], 1);
}

__global__ __launch_bounds__(256) void k_dis(const int* __restrict__ deg, float* __restrict__ dis) {
  int i = blockIdx.x * 256 + threadIdx.x;
  if (i < NN) { int d = deg[i]; dis[i] = d > 0 ? rsqrtf((float)d) : 0.f; }
}

__global__ __launch_bounds__(256) void k_scan1(const int* __restrict__ deg, int* __restrict__ rowStart,
                                               int* __restrict__ bsum) {
  __shared__ int s[256];
  int tid = threadIdx.x;
  int i = blockIdx.x * 256 + tid;        // 625*256 = NN exact
  int v = deg[i];
  s[tid] = v;
  __syncthreads();
  for (int off = 1; off < 256; off <<= 1) {
    int t = (tid >= off) ? s[tid - off] : 0;
    __syncthreads();
    s[tid] += t;
    __syncthreads();
  }
  rowStart[i] = s[tid] - v;
  if (tid == 255) bsum[blockIdx.x] = s[255];
}

__global__ void k_scan2(int* __restrict__ bsum, int nb) {
  __shared__ int s[1024];
  int tid = threadIdx.x;
  int v = (tid < nb) ? bsum[tid] : 0;
  s[tid] = v;
  __syncthreads();
  for (int off = 1; off < 1024; off <<= 1) {
    int t = (tid >= off) ? s[tid - off] : 0;
    __syncthreads();
    s[tid] += t;
    __syncthreads();
  }
  if (tid < nb) bsum[tid] = s[tid] - v;
}

__global__ __launch_bounds__(256) void k_scan3(int* __restrict__ rowStart, const int* __restrict__ bsum) {
  int i = blockIdx.x * 256 + threadIdx.x;
  rowStart[i] += bsum[blockIdx.x];
  if (i == 0) rowStart[NN] = EE;
}

__global__ __launch_bounds__(256) void k_scatter(const int* __restrict__ ei, const int* __restrict__ rowStart,
                                                 int* __restrict__ cursor, const float* __restrict__ dis,
                                                 int2* __restrict__ ew) {
  int e = blockIdx.x * 256 + threadIdx.x;
  if (e >= EE) return;
  int r = ei[e];
  int c = ei[EE + e];
  int pos = rowStart[r] + atomicAdd(&cursor[r], 1);
  ew[pos] = make_int2(c, __float_as_int(-dis[r] * dis[c]));
}

// ----------------- Layer 0 (cin=3) classic Chebyshev -----------------
__global__ __launch_bounds__(256) void k_copyx(const float* __restrict__ x, float* __restrict__ A,
                                               unsigned short* __restrict__ TxAll) {
  int i = blockIdx.x * 256 + threadIdx.x;     // over NN*3
  if (i < NN * 3) {
    float v = x[i];
    A[i] = v;
    int node = i / 3, c = i - node * 3;
    TxAll[node * 32 + c] = f2h(v);
  }
}

template <int MODE>   // 1: Tx1 = prop(Tx0); 2: Tnew = 2*prop(Tsrc) - Tdst (in place)
__global__ __launch_bounds__(256) void k_prop3(const float* __restrict__ Tsrc, float* __restrict__ Tdst,
                                               unsigned short* __restrict__ TxAll, int ks,
                                               const int* __restrict__ rowStart, const int2* __restrict__ ew) {
  int i = blockIdx.x * 256 + threadIdx.x;
  if (i >= NN) return;
  float a0 = 0.f, a1 = 0.f, a2 = 0.f;
  int e = rowStart[i], e1 = rowStart[i + 1];
  for (; e + 1 < e1; e += 2) {
    int2 p0 = ew[e], p1 = ew[e + 1];
    float w0 = __int_as_float(p0.y), w1 = __int_as_float(p1.y);
    a0 += w0 * Tsrc[p0.x * 3] + w1 * Tsrc[p1.x * 3];
    a1 += w0 * Tsrc[p0.x * 3 + 1] + w1 * Tsrc[p1.x * 3 + 1];
    a2 += w0 * Tsrc[p0.x * 3 + 2] + w1 * Tsrc[p1.x * 3 + 2];
  }
  if (e < e1) {
    int2 p0 = ew[e];
    float w0 = __int_as_float(p0.y);
    a0 += w0 * Tsrc[p0.x * 3];
    a1 += w0 * Tsrc[p0.x * 3 + 1];
    a2 += w0 * Tsrc[p0.x * 3 + 2];
  }
  if (MODE == 2) {
    a0 = 2.f * a0 - Tdst[i * 3];
    a1 = 2.f * a1 - Tdst[i * 3 + 1];
    a2 = 2.f * a2 - Tdst[i * 3 + 2];
  }
  Tdst[i * 3] = a0; Tdst[i * 3 + 1] = a1; Tdst[i * 3 + 2] = a2;
  unsigned short* tp = TxAll + i * 32 + ks * 3;
  tp[0] = f2h(a0); tp[1] = f2h(a1); tp[2] = f2h(a2);
}

// W0 (18 x 128) -> transposed padded fp16 (128 x 32)
__global__ __launch_bounds__(256) void k_padW0(const float* __restrict__ W0, unsigned short* __restrict__ Bt) {
  int idx = blockIdx.x * 256 + threadIdx.x;   // 128*32
  if (idx >= 128 * 32) return;
  int co = idx >> 5, t = idx & 31;
  Bt[co * 32 + t] = (t < 18) ? f2h(W0[t * 128 + co]) : (unsigned short)0;
}

// C_j = sum_k a[k][j] W_k, written TRANSPOSED fp16: Bt[(j*COUT+co)*CIN + ci]
template <int CIN, int COUT>
__global__ __launch_bounds__(256) void k_combine(const float* __restrict__ W, unsigned short* __restrict__ Bt) {
  int idx = blockIdx.x * 256 + threadIdx.x;
  if (idx >= CIN * 6 * COUT) return;
  int co = idx % COUT;
  int j  = (idx / COUT) % 6;
  int ci = idx / (6 * COUT);
  float c0, c1, c2, c3, c4, c5;
  switch (j) {
    case 0:  c0 = 1;  c1 = 0;  c2 = -1; c3 = 0;   c4 = 1;  c5 = 0;   break;
    case 1:  c0 = 0;  c1 = 1;  c2 = 0;  c3 = -3;  c4 = 0;  c5 = 5;   break;
    case 2:  c0 = 0;  c1 = 0;  c2 = 2;  c3 = 0;   c4 = -8; c5 = 0;   break;
    case 3:  c0 = 0;  c1 = 0;  c2 = 0;  c3 = 4;   c4 = 0;  c5 = -20; break;
    case 4:  c0 = 0;  c1 = 0;  c2 = 0;  c3 = 0;   c4 = 8;  c5 = 0;   break;
    default: c0 = 0;  c1 = 0;  c2 = 0;  c3 = 0;   c4 = 0;  c5 = 16;  break;
  }
  float s = 0.f;
  s += c0 * W[(0 * CIN + ci) * COUT + co];
  s += c1 * W[(1 * CIN + ci) * COUT + co];
  s += c2 * W[(2 * CIN + ci) * COUT + co];
  s += c3 * W[(3 * CIN + ci) * COUT + co];
  s += c4 * W[(4 * CIN + ci) * COUT + co];
  s += c5 * W[(5 * CIN + ci) * COUT + co];
  Bt[(j * COUT + co) * CIN + ci] = f2h(s);
}

// ----------------- MFMA f16 GEMM: (N x KDIM) @ Bt(ncol x KDIM)^T -> Y fp16 ----------
// grid (NN/64, ncol/64), 256 thr (4 waves), wave w -> rows 16w..16w+15, all 64 cols.
template <int KDIM, int COUT>
__global__ __launch_bounds__(256) void k_gemm(const unsigned short* __restrict__ A,
                                              const unsigned short* __restrict__ Bt,
                                              unsigned short* __restrict__ Y) {
  constexpr int KP = KDIM + 8;                 // pad: 16B-aligned rows, 2-way-max bank alias
  __shared__ unsigned short As[64 * KP];
  __shared__ unsigned short Bs[64 * KP];
  int i0 = blockIdx.x * 64;
  int c0 = blockIdx.y * 64;
  for (int idx = threadIdx.x; idx < 64 * (KDIM / 8); idx += 256) {
    int row = idx / (KDIM / 8), seg = idx % (KDIM / 8);
    uint4 v = ((const uint4*)A)[(size_t)(i0 + row) * (KDIM / 8) + seg];
    *reinterpret_cast<uint4*>(&As[row * KP + seg * 8]) = v;
  }
  for (int idx = threadIdx.x; idx < 64 * (KDIM / 8); idx += 256) {
    int row = idx / (KDIM / 8), seg = idx % (KDIM / 8);
    uint4 v = ((const uint4*)Bt)[(size_t)(c0 + row) * (KDIM / 8) + seg];
    *reinterpret_cast<uint4*>(&Bs[row * KP + seg * 8]) = v;
  }
  __syncthreads();
  int w = threadIdx.x >> 6, lane = threadIdx.x & 63;
  int mn = lane & 15, q = lane >> 4;
  floatx4 acc[4];
#pragma unroll
  for (int cb = 0; cb < 4; cb++) acc[cb] = {0.f, 0.f, 0.f, 0.f};
#pragma unroll
  for (int ks = 0; ks < KDIM / 32; ks++) {
    half8 af = *reinterpret_cast<const half8*>(&As[(16 * w + mn) * KP + ks * 32 + q * 8]);
#pragma unroll
    for (int cb = 0; cb < 4; cb++) {
      half8 bf = *reinterpret_cast<const half8*>(&Bs[(cb * 16 + mn) * KP + ks * 32 + q * 8]);
      acc[cb] = __builtin_amdgcn_mfma_f32_16x16x32_f16(af, bf, acc[cb], 0, 0, 0);
    }
  }
  // C/D layout: col = lane&15, row = (lane>>4)*4 + reg  [m89; dtype-independent m121/m124]
#pragma unroll
  for (int cb = 0; cb < 4; cb++) {
    int jc = c0 + cb * 16 + mn;
    int slice = jc / COUT, cc = jc % COUT;
    unsigned short* dst = Y + (size_t)slice * NN * COUT + cc;
#pragma unroll
    for (int r = 0; r < 4; r++) {
      int i = i0 + 16 * w + q * 4 + r;
      dst[(size_t)i * COUT] = f2h(acc[cb][r]);
    }
  }
}

// ----------------- Horner prop step (fp16): Ydst += L * Ysrc, in cout space ---------
// CPN = channel-pairs per node (C/2). Thread -> (node, pair). Grid exact.
template <int CPN>
__global__ __launch_bounds__(256) void k_horner(const unsigned* __restrict__ Ysrc, unsigned* __restrict__ Ydst,
                                                const int* __restrict__ rowStart, const int2* __restrict__ ew) {
  int t = blockIdx.x * 256 + threadIdx.x;
  int i = t / CPN;
  int cp = t % CPN;
  float2 a = h2f2(Ydst[(size_t)i * CPN + cp]);
  float acc0 = a.x, acc1 = a.y;
  int e = rowStart[i], e1 = rowStart[i + 1];
  for (; e + 3 < e1; e += 4) {
    int2 p0 = ew[e], p1 = ew[e + 1], p2 = ew[e + 2], p3 = ew[e + 3];
    unsigned u0 = Ysrc[(size_t)p0.x * CPN + cp];
    unsigned u1 = Ysrc[(size_t)p1.x * CPN + cp];
    unsigned u2 = Ysrc[(size_t)p2.x * CPN + cp];
    unsigned u3 = Ysrc[(size_t)p3.x * CPN + cp];
    float w0 = __int_as_float(p0.y), w1 = __int_as_float(p1.y);
    float w2 = __int_as_float(p2.y), w3 = __int_as_float(p3.y);
    float2 f0 = h2f2(u0), f1 = h2f2(u1), f2 = h2f2(u2), f3 = h2f2(u3);
    acc0 += w0 * f0.x + w1 * f1.x + w2 * f2.x + w3 * f3.x;
    acc1 += w0 * f0.y + w1 * f1.y + w2 * f2.y + w3 * f3.y;
  }
  for (; e < e1; e++) {
    int2 p0 = ew[e];
    float w0 = __int_as_float(p0.y);
    float2 f0 = h2f2(Ysrc[(size_t)p0.x * CPN + cp]);
    acc0 += w0 * f0.x;
    acc1 += w0 * f0.y;
  }
  Ydst[(size_t)i * CPN + cp] = packh2(acc0, acc1);
}

// ----------------- GroupNorm(8) + bias + ReLU (fp16 in/out) -----------------
template <int CPG>
__global__ __launch_bounds__(256) void k_gn(const unsigned short* __restrict__ src, const float* __restrict__ bias,
                                            const float* __restrict__ gamma, const float* __restrict__ beta,
                                            unsigned short* __restrict__ dst) {
  constexpr int C = CPG * 8;
  int t = blockIdx.x * 256 + threadIdx.x;   // (node, group); grid 5000*256 = NN*8 exact
  int i = t >> 3, g = t & 7;
  float v[CPG];
  const unsigned* p = reinterpret_cast<const unsigned*>(src + (size_t)i * C + g * CPG);
#pragma unroll
  for (int q = 0; q < CPG / 2; q++) {
    float2 f = h2f2(p[q]);
    v[2 * q] = f.x; v[2 * q + 1] = f.y;
  }
  float mean = 0.f;
#pragma unroll
  for (int c = 0; c < CPG; c++) { v[c] += bias[g * CPG + c]; mean += v[c]; }
  mean *= (1.f / CPG);
  float var = 0.f;
#pragma unroll
  for (int c = 0; c < CPG; c++) { float d = v[c] - mean; var += d * d; }
  var *= (1.f / CPG);
  float rs = rsqrtf(var + 1e-5f);
  unsigned* dp = reinterpret_cast<unsigned*>(dst + (size_t)i * C + g * CPG);
#pragma unroll
  for (int q = 0; q < CPG / 2; q++) {
    float o0 = fmaxf((v[2 * q] - mean) * rs * gamma[g * CPG + 2 * q] + beta[g * CPG + 2 * q], 0.f);
    float o1 = fmaxf((v[2 * q + 1] - mean) * rs * gamma[g * CPG + 2 * q + 1] + beta[g * CPG + 2 * q + 1], 0.f);
    dp[q] = packh2(o0, o1);
  }
}

// ----------------- Readout: (16 x 320000) @ (320000 x 128), split-K + atomics --------
__global__ __launch_bounds__(256) void k_initout(const float* __restrict__ bl, float* __restrict__ out) {
  int t = blockIdx.x * 256 + threadIdx.x;
  if (t < 2048) out[t] = bl[t & 127];
}

__global__ __launch_bounds__(256) void k_final(const unsigned short* __restrict__ h3, const float* __restrict__ Wl,
                                               float* __restrict__ out) {
  __shared__ float hs[16 * FDC];
  int d0 = blockIdx.x * FDC;
  const unsigned* h3u = reinterpret_cast<const unsigned*>(h3);
  for (int idx = threadIdx.x; idx < 16 * (FDC / 8); idx += 256) {
    int b = idx / (FDC / 8), dq = idx % (FDC / 8);
    uint4 v = ((const uint4*)h3u)[(size_t)b * 40000 + (size_t)d0 / 8 + dq];
    float2 f0 = h2f2(v.x), f1 = h2f2(v.y), f2 = h2f2(v.z), f3 = h2f2(v.w);
    float* hp = &hs[b * FDC + dq * 8];
    hp[0] = f0.x; hp[1] = f0.y; hp[2] = f1.x; hp[3] = f1.y;
    hp[4] = f2.x; hp[5] = f2.y; hp[6] = f3.x; hp[7] = f3.y;
  }
  __syncthreads();
  int w = threadIdx.x >> 6, lane = threadIdx.x & 63;
  int bh = w & 1, ds = w >> 1;
  float acc0[8], acc1[8];
#pragma unroll
  for (int bb = 0; bb < 8; bb++) { acc0[bb] = 0.f; acc1[bb] = 0.f; }
  for (int dd = ds; dd < FDC; dd += 2) {
    float w0 = Wl[(size_t)(d0 + dd) * 128 + lane];
    float w1 = Wl[(size_t)(d0 + dd) * 128 + lane + 64];
#pragma unroll
    for (int bb = 0; bb < 8; bb++) {
      float h = hs[(bh * 8 + bb) * FDC + dd];
      acc0[bb] += w0 * h;
      acc1[bb] += w1 * h;
    }
  }
#pragma unroll
  for (int bb = 0; bb < 8; bb++) {
    atomicAdd(&out[(bh * 8 + bb) * 128 + lane], acc0[bb]);
    atomicAdd(&out[(bh * 8 + bb) * 128 + lane + 64], acc1[bb]);
  }
}

// ----------------- launcher -----------------
extern "C" void kernel_launch(void* const* d_in, const int* in_sizes, int n_in,
                              void* d_out, int out_size, void* d_ws, size_t ws_size,
                              hipStream_t stream) {
  const float* x   = (const float*)d_in[0];
  const int*   ei  = (const int*)d_in[1];   // harness stages ALL integer inputs as int32
  const float* W0  = (const float*)d_in[2];
  const float* b0  = (const float*)d_in[3];
  const float* g0  = (const float*)d_in[4];
  const float* be0 = (const float*)d_in[5];
  const float* W1  = (const float*)d_in[6];
  const float* b1  = (const float*)d_in[7];
  const float* g1  = (const float*)d_in[8];
  const float* be1 = (const float*)d_in[9];
  const float* W2  = (const float*)d_in[10];
  const float* b2  = (const float*)d_in[11];
  const float* g2  = (const float*)d_in[12];
  const float* be2 = (const float*)d_in[13];
  const float* Wl  = (const float*)d_in[14];
  const float* bl  = (const float*)d_in[15];
  float* out = (float*)d_out;
  (void)in_sizes; (void)n_in; (void)out_size; (void)ws_size;

  char* pw = (char*)d_ws;
  auto carve = [&](size_t bytes) -> void* {
    void* r = (void*)pw;
    pw += (bytes + 255) & ~(size_t)255;
    return r;
  };
  int*            deg      = (int*)   carve((size_t)NN * 4);
  int*            cursor   = (int*)   carve((size_t)NN * 4);
  int*            rowStart = (int*)   carve((size_t)(NN + 1) * 4);
  int*            bsum     = (int*)   carve(1024 * 4);
  float*          dis      = (float*) carve((size_t)NN * 4);
  int2*           ew       = (int2*)  carve((size_t)EE * 8);
  unsigned short* Cwt      = (unsigned short*)carve((size_t)384 * 128 * 2);
  unsigned short* TxAll    = (unsigned short*)carve((size_t)NN * 32 * 2);
  float*          A3       = (float*) carve((size_t)NN * 3 * 4);
  float*          B3       = (float*) carve((size_t)NN * 3 * 4);
  unsigned short* Hbuf     = (unsigned short*)carve((size_t)NN * 128 * 2);
  unsigned short* Ybuf     = (unsigned short*)carve((size_t)NN * 384 * 2);

  // ---- CSR build ----
  k_zero<<<625, 256, 0, stream>>>(deg, NN);
  k_zero<<<625, 256, 0, stream>>>(cursor, NN);
  k_hist<<<10000, 256, 0, stream>>>(ei, deg);
  k_dis<<<625, 256, 0, stream>>>(deg, dis);
  k_scan1<<<625, 256, 0, stream>>>(deg, rowStart, bsum);
  k_scan2<<<1, 1024, 0, stream>>>(bsum, 625);
  k_scan3<<<625, 256, 0, stream>>>(rowStart, bsum);
  k_scatter<<<10000, 256, 0, stream>>>(ei, rowStart, cursor, dis, ew);

  // ---- Layer 0 (3 -> 128): classic Chebyshev, TxAll (NN x 32 fp16, zero-pad) ----
  k_zero<<<10000, 256, 0, stream>>>((int*)TxAll, NN * 16);
  k_copyx<<<1875, 256, 0, stream>>>(x, A3, TxAll);
  k_prop3<1><<<625, 256, 0, stream>>>(A3, B3, TxAll, 1, rowStart, ew);
  k_prop3<2><<<625, 256, 0, stream>>>(B3, A3, TxAll, 2, rowStart, ew);
  k_prop3<2><<<625, 256, 0, stream>>>(A3, B3, TxAll, 3, rowStart, ew);
  k_prop3<2><<<625, 256, 0, stream>>>(B3, A3, TxAll, 4, rowStart, ew);
  k_prop3<2><<<625, 256, 0, stream>>>(A3, B3, TxAll, 5, rowStart, ew);
  k_padW0<<<16, 256, 0, stream>>>(W0, Cwt);
  k_gemm<32, 128><<<dim3(2500, 2), 256, 0, stream>>>(TxAll, Cwt, Ybuf);
  k_gn<16><<<5000, 256, 0, stream>>>(Ybuf, b0, g0, be0, Hbuf);

  // ---- Layer 1 (128 -> 64): one MFMA GEMM + 5 Horner props in cout space ----
  k_combine<128, 64><<<192, 256, 0, stream>>>(W1, Cwt);
  k_gemm<128, 64><<<dim3(2500, 6), 256, 0, stream>>>(Hbuf, Cwt, Ybuf);
  for (int j = 4; j >= 0; j--)
    k_horner<32><<<20000, 256, 0, stream>>>((unsigned*)(Ybuf + (size_t)(j + 1) * NN * 64),
                                            (unsigned*)(Ybuf + (size_t)j * NN * 64), rowStart, ew);
  k_gn<8><<<5000, 256, 0, stream>>>(Ybuf, b1, g1, be1, Hbuf);

  // ---- Layer 2 (64 -> 32) ----
  k_combine<64, 32><<<48, 256, 0, stream>>>(W2, Cwt);
  k_gemm<64, 32><<<dim3(2500, 3), 256, 0, stream>>>(Hbuf, Cwt, Ybuf);
  for (int j = 4; j >= 0; j--)
    k_horner<16><<<10000, 256, 0, stream>>>((unsigned*)(Ybuf + (size_t)(j + 1) * NN * 32),
                                            (unsigned*)(Ybuf + (size_t)j * NN * 32), rowStart, ew);
  k_gn<4><<<5000, 256, 0, stream>>>(Ybuf, b2, g2, be2, Hbuf);

  // ---- Readout ----
  k_initout<<<8, 256, 0, stream>>>(bl, out);
  k_final<<<500, 256, 0, stream>>>(Hbuf, Wl, out);
}

// Round 5
// 1436.196 us; speedup vs baseline: 1.6730x; 1.0348x over previous
//
#include <hip/hip_runtime.h>
#include <hip/hip_fp16.h>

// GraphEncoder: 3x ChebConv(K=6) + GroupNorm(8)/ReLU + dense readout.
// R5: readout restructured (R4's k_final was grid-limited: 500 blocks = 1.9/CU,
//     174 us at 548 GB/s). Now 2-stage split-K: 1250 blocks -> 2048 partials
//     each -> 8-block reduce. Horner 8-edge unroll, prop3 4-edge unroll.
// R4: fp16 intermediates (bf16 7-bit mantissa overshot threshold), fp32 accum.

#define NN 160000
#define EE 2560000
#define FD2 256

typedef __attribute__((ext_vector_type(8))) _Float16 half8;
typedef __attribute__((ext_vector_type(4))) float floatx4;

__device__ inline float2 h2f2(unsigned u) {
  __half2 h = __builtin_bit_cast(__half2, u);
  return __half22float2(h);
}
__device__ inline unsigned short f2h(float f) {
  return __builtin_bit_cast(unsigned short, __float2half_rn(f));
}
__device__ inline unsigned packh2(float a, float b) {
  return __builtin_bit_cast(unsigned, __floats2half2_rn(a, b));
}

// ----------------- CSR build -----------------
__global__ __launch_bounds__(256) void k_zero(int* __restrict__ p, int n) {
  int i = blockIdx.x * 256 + threadIdx.x;
  if (i < n) p[i] = 0;
}

__global__ __launch_bounds__(256) void k_hist(const int* __restrict__ ei, int* __restrict__ deg) {
  int e = blockIdx.x * 256 + threadIdx.x;
  if (e < EE) atomicAdd(&deg[ei[e]], 1);
}

__global__ __launch_bounds__(256) void k_dis(const int* __restrict__ deg, float* __restrict__ dis) {
  int i = blockIdx.x * 256 + threadIdx.x;
  if (i < NN) { int d = deg[i]; dis[i] = d > 0 ? rsqrtf((float)d) : 0.f; }
}

__global__ __launch_bounds__(256) void k_scan1(const int* __restrict__ deg, int* __restrict__ rowStart,
                                               int* __restrict__ bsum) {
  __shared__ int s[256];
  int tid = threadIdx.x;
  int i = blockIdx.x * 256 + tid;        // 625*256 = NN exact
  int v = deg[i];
  s[tid] = v;
  __syncthreads();
  for (int off = 1; off < 256; off <<= 1) {
    int t = (tid >= off) ? s[tid - off] : 0;
    __syncthreads();
    s[tid] += t;
    __syncthreads();
  }
  rowStart[i] = s[tid] - v;
  if (tid == 255) bsum[blockIdx.x] = s[255];
}

__global__ void k_scan2(int* __restrict__ bsum, int nb) {
  __shared__ int s[1024];
  int tid = threadIdx.x;
  int v = (tid < nb) ? bsum[tid] : 0;
  s[tid] = v;
  __syncthreads();
  for (int off = 1; off < 1024; off <<= 1) {
    int t = (tid >= off) ? s[tid - off] : 0;
    __syncthreads();
    s[tid] += t;
    __syncthreads();
  }
  if (tid < nb) bsum[tid] = s[tid] - v;
}

__global__ __launch_bounds__(256) void k_scan3(int* __restrict__ rowStart, const int* __restrict__ bsum) {
  int i = blockIdx.x * 256 + threadIdx.x;
  rowStart[i] += bsum[blockIdx.x];
  if (i == 0) rowStart[NN] = EE;
}

__global__ __launch_bounds__(256) void k_scatter(const int* __restrict__ ei, const int* __restrict__ rowStart,
                                                 int* __restrict__ cursor, const float* __restrict__ dis,
                                                 int2* __restrict__ ew) {
  int e = blockIdx.x * 256 + threadIdx.x;
  if (e >= EE) return;
  int r = ei[e];
  int c = ei[EE + e];
  int pos = rowStart[r] + atomicAdd(&cursor[r], 1);
  ew[pos] = make_int2(c, __float_as_int(-dis[r] * dis[c]));
}

// ----------------- Layer 0 (cin=3) classic Chebyshev -----------------
__global__ __launch_bounds__(256) void k_copyx(const float* __restrict__ x, float* __restrict__ A,
                                               unsigned short* __restrict__ TxAll) {
  int i = blockIdx.x * 256 + threadIdx.x;     // over NN*3
  if (i < NN * 3) {
    float v = x[i];
    A[i] = v;
    int node = i / 3, c = i - node * 3;
    TxAll[node * 32 + c] = f2h(v);
  }
}

template <int MODE>   // 1: Tx1 = prop(Tx0); 2: Tnew = 2*prop(Tsrc) - Tdst (in place)
__global__ __launch_bounds__(256) void k_prop3(const float* __restrict__ Tsrc, float* __restrict__ Tdst,
                                               unsigned short* __restrict__ TxAll, int ks,
                                               const int* __restrict__ rowStart, const int2* __restrict__ ew) {
  int i = blockIdx.x * 256 + threadIdx.x;
  if (i >= NN) return;
  float a0 = 0.f, a1 = 0.f, a2 = 0.f;
  int e = rowStart[i], e1 = rowStart[i + 1];
  for (; e + 3 < e1; e += 4) {
    int2 p0 = ew[e], p1 = ew[e + 1], p2 = ew[e + 2], p3 = ew[e + 3];
    float w0 = __int_as_float(p0.y), w1 = __int_as_float(p1.y);
    float w2 = __int_as_float(p2.y), w3 = __int_as_float(p3.y);
    a0 += w0 * Tsrc[p0.x * 3] + w1 * Tsrc[p1.x * 3] + w2 * Tsrc[p2.x * 3] + w3 * Tsrc[p3.x * 3];
    a1 += w0 * Tsrc[p0.x * 3 + 1] + w1 * Tsrc[p1.x * 3 + 1] + w2 * Tsrc[p2.x * 3 + 1] + w3 * Tsrc[p3.x * 3 + 1];
    a2 += w0 * Tsrc[p0.x * 3 + 2] + w1 * Tsrc[p1.x * 3 + 2] + w2 * Tsrc[p2.x * 3 + 2] + w3 * Tsrc[p3.x * 3 + 2];
  }
  for (; e < e1; e++) {
    int2 p0 = ew[e];
    float w0 = __int_as_float(p0.y);
    a0 += w0 * Tsrc[p0.x * 3];
    a1 += w0 * Tsrc[p0.x * 3 + 1];
    a2 += w0 * Tsrc[p0.x * 3 + 2];
  }
  if (MODE == 2) {
    a0 = 2.f * a0 - Tdst[i * 3];
    a1 = 2.f * a1 - Tdst[i * 3 + 1];
    a2 = 2.f * a2 - Tdst[i * 3 + 2];
  }
  Tdst[i * 3] = a0; Tdst[i * 3 + 1] = a1; Tdst[i * 3 + 2] = a2;
  unsigned short* tp = TxAll + i * 32 + ks * 3;
  tp[0] = f2h(a0); tp[1] = f2h(a1); tp[2] = f2h(a2);
}

// W0 (18 x 128) -> transposed padded fp16 (128 x 32)
__global__ __launch_bounds__(256) void k_padW0(const float* __restrict__ W0, unsigned short* __restrict__ Bt) {
  int idx = blockIdx.x * 256 + threadIdx.x;   // 128*32
  if (idx >= 128 * 32) return;
  int co = idx >> 5, t = idx & 31;
  Bt[co * 32 + t] = (t < 18) ? f2h(W0[t * 128 + co]) : (unsigned short)0;
}

// C_j = sum_k a[k][j] W_k, written TRANSPOSED fp16: Bt[(j*COUT+co)*CIN + ci]
template <int CIN, int COUT>
__global__ __launch_bounds__(256) void k_combine(const float* __restrict__ W, unsigned short* __restrict__ Bt) {
  int idx = blockIdx.x * 256 + threadIdx.x;
  if (idx >= CIN * 6 * COUT) return;
  int co = idx % COUT;
  int j  = (idx / COUT) % 6;
  int ci = idx / (6 * COUT);
  float c0, c1, c2, c3, c4, c5;
  switch (j) {
    case 0:  c0 = 1;  c1 = 0;  c2 = -1; c3 = 0;   c4 = 1;  c5 = 0;   break;
    case 1:  c0 = 0;  c1 = 1;  c2 = 0;  c3 = -3;  c4 = 0;  c5 = 5;   break;
    case 2:  c0 = 0;  c1 = 0;  c2 = 2;  c3 = 0;   c4 = -8; c5 = 0;   break;
    case 3:  c0 = 0;  c1 = 0;  c2 = 0;  c3 = 4;   c4 = 0;  c5 = -20; break;
    case 4:  c0 = 0;  c1 = 0;  c2 = 0;  c3 = 0;   c4 = 8;  c5 = 0;   break;
    default: c0 = 0;  c1 = 0;  c2 = 0;  c3 = 0;   c4 = 0;  c5 = 16;  break;
  }
  float s = 0.f;
  s += c0 * W[(0 * CIN + ci) * COUT + co];
  s += c1 * W[(1 * CIN + ci) * COUT + co];
  s += c2 * W[(2 * CIN + ci) * COUT + co];
  s += c3 * W[(3 * CIN + ci) * COUT + co];
  s += c4 * W[(4 * CIN + ci) * COUT + co];
  s += c5 * W[(5 * CIN + ci) * COUT + co];
  Bt[(j * COUT + co) * CIN + ci] = f2h(s);
}

// ----------------- MFMA f16 GEMM: (N x KDIM) @ Bt(ncol x KDIM)^T -> Y fp16 ----------
template <int KDIM, int COUT>
__global__ __launch_bounds__(256) void k_gemm(const unsigned short* __restrict__ A,
                                              const unsigned short* __restrict__ Bt,
                                              unsigned short* __restrict__ Y) {
  constexpr int KP = KDIM + 8;
  __shared__ unsigned short As[64 * KP];
  __shared__ unsigned short Bs[64 * KP];
  int i0 = blockIdx.x * 64;
  int c0 = blockIdx.y * 64;
  for (int idx = threadIdx.x; idx < 64 * (KDIM / 8); idx += 256) {
    int row = idx / (KDIM / 8), seg = idx % (KDIM / 8);
    uint4 v = ((const uint4*)A)[(size_t)(i0 + row) * (KDIM / 8) + seg];
    *reinterpret_cast<uint4*>(&As[row * KP + seg * 8]) = v;
  }
  for (int idx = threadIdx.x; idx < 64 * (KDIM / 8); idx += 256) {
    int row = idx / (KDIM / 8), seg = idx % (KDIM / 8);
    uint4 v = ((const uint4*)Bt)[(size_t)(c0 + row) * (KDIM / 8) + seg];
    *reinterpret_cast<uint4*>(&Bs[row * KP + seg * 8]) = v;
  }
  __syncthreads();
  int w = threadIdx.x >> 6, lane = threadIdx.x & 63;
  int mn = lane & 15, q = lane >> 4;
  floatx4 acc[4];
#pragma unroll
  for (int cb = 0; cb < 4; cb++) acc[cb] = {0.f, 0.f, 0.f, 0.f};
#pragma unroll
  for (int ks = 0; ks < KDIM / 32; ks++) {
    half8 af = *reinterpret_cast<const half8*>(&As[(16 * w + mn) * KP + ks * 32 + q * 8]);
#pragma unroll
    for (int cb = 0; cb < 4; cb++) {
      half8 bf = *reinterpret_cast<const half8*>(&Bs[(cb * 16 + mn) * KP + ks * 32 + q * 8]);
      acc[cb] = __builtin_amdgcn_mfma_f32_16x16x32_f16(af, bf, acc[cb], 0, 0, 0);
    }
  }
  // C/D layout: col = lane&15, row = (lane>>4)*4 + reg  [m89; dtype-independent]
#pragma unroll
  for (int cb = 0; cb < 4; cb++) {
    int jc = c0 + cb * 16 + mn;
    int slice = jc / COUT, cc = jc % COUT;
    unsigned short* dst = Y + (size_t)slice * NN * COUT + cc;
#pragma unroll
    for (int r = 0; r < 4; r++) {
      int i = i0 + 16 * w + q * 4 + r;
      dst[(size_t)i * COUT] = f2h(acc[cb][r]);
    }
  }
}

// ----------------- Horner prop step (fp16): Ydst += L * Ysrc, in cout space ---------
template <int CPN>
__global__ __launch_bounds__(256) void k_horner(const unsigned* __restrict__ Ysrc, unsigned* __restrict__ Ydst,
                                                const int* __restrict__ rowStart, const int2* __restrict__ ew) {
  int t = blockIdx.x * 256 + threadIdx.x;
  int i = t / CPN;
  int cp = t % CPN;
  float2 a = h2f2(Ydst[(size_t)i * CPN + cp]);
  float acc0 = a.x, acc1 = a.y;
  int e = rowStart[i], e1 = rowStart[i + 1];
  for (; e + 7 < e1; e += 8) {
    int2 p[8];
    unsigned u[8];
#pragma unroll
    for (int k = 0; k < 8; k++) p[k] = ew[e + k];
#pragma unroll
    for (int k = 0; k < 8; k++) u[k] = Ysrc[(size_t)p[k].x * CPN + cp];
#pragma unroll
    for (int k = 0; k < 8; k++) {
      float w = __int_as_float(p[k].y);
      float2 f = h2f2(u[k]);
      acc0 += w * f.x;
      acc1 += w * f.y;
    }
  }
  for (; e < e1; e++) {
    int2 p0 = ew[e];
    float w0 = __int_as_float(p0.y);
    float2 f0 = h2f2(Ysrc[(size_t)p0.x * CPN + cp]);
    acc0 += w0 * f0.x;
    acc1 += w0 * f0.y;
  }
  Ydst[(size_t)i * CPN + cp] = packh2(acc0, acc1);
}

// ----------------- GroupNorm(8) + bias + ReLU (fp16 in/out) -----------------
template <int CPG>
__global__ __launch_bounds__(256) void k_gn(const unsigned short* __restrict__ src, const float* __restrict__ bias,
                                            const float* __restrict__ gamma, const float* __restrict__ beta,
                                            unsigned short* __restrict__ dst) {
  constexpr int C = CPG * 8;
  int t = blockIdx.x * 256 + threadIdx.x;   // (node, group); grid 5000*256 = NN*8 exact
  int i = t >> 3, g = t & 7;
  float v[CPG];
  const unsigned* p = reinterpret_cast<const unsigned*>(src + (size_t)i * C + g * CPG);
#pragma unroll
  for (int q = 0; q < CPG / 2; q++) {
    float2 f = h2f2(p[q]);
    v[2 * q] = f.x; v[2 * q + 1] = f.y;
  }
  float mean = 0.f;
#pragma unroll
  for (int c = 0; c < CPG; c++) { v[c] += bias[g * CPG + c]; mean += v[c]; }
  mean *= (1.f / CPG);
  float var = 0.f;
#pragma unroll
  for (int c = 0; c < CPG; c++) { float d = v[c] - mean; var += d * d; }
  var *= (1.f / CPG);
  float rs = rsqrtf(var + 1e-5f);
  unsigned* dp = reinterpret_cast<unsigned*>(dst + (size_t)i * C + g * CPG);
#pragma unroll
  for (int q = 0; q < CPG / 2; q++) {
    float o0 = fmaxf((v[2 * q] - mean) * rs * gamma[g * CPG + 2 * q] + beta[g * CPG + 2 * q], 0.f);
    float o1 = fmaxf((v[2 * q + 1] - mean) * rs * gamma[g * CPG + 2 * q + 1] + beta[g * CPG + 2 * q + 1], 0.f);
    dp[q] = packh2(o0, o1);
  }
}

// ----------------- Readout: (16 x 320000) @ (320000 x 128), 2-stage split-K ----------
// Stage 1: 1250 blocks x 256 dims each. Per-lane float2 cols, 16 batch accumulators,
// cross-wave LDS reduce, write 2048 partials per block (no atomics).
__global__ __launch_bounds__(256) void k_final1(const unsigned short* __restrict__ h3,
                                                const float* __restrict__ Wl,
                                                float* __restrict__ part) {
  __shared__ float hs[16 * FD2];     // 16 KB
  __shared__ float red[2048];        // 8 KB
  int d0 = blockIdx.x * FD2;
  const unsigned* h3u = reinterpret_cast<const unsigned*>(h3);
  for (int idx = threadIdx.x; idx < 16 * (FD2 / 2); idx += 256) {
    int b = idx / (FD2 / 2), dq = idx % (FD2 / 2);
    float2 f = h2f2(h3u[(size_t)b * 160000 + (d0 >> 1) + dq]);
    hs[b * FD2 + 2 * dq] = f.x;
    hs[b * FD2 + 2 * dq + 1] = f.y;
  }
  __syncthreads();
  int w = threadIdx.x >> 6, lane = threadIdx.x & 63;
  float a0[16], a1[16];
#pragma unroll
  for (int b = 0; b < 16; b++) { a0[b] = 0.f; a1[b] = 0.f; }
  const float* wp = Wl + (size_t)(d0 + w * (FD2 / 4)) * 128 + 2 * lane;
#pragma unroll 2
  for (int r = 0; r < FD2 / 4; r++) {
    float2 wv = *reinterpret_cast<const float2*>(wp + (size_t)r * 128);
    int row = w * (FD2 / 4) + r;
#pragma unroll
    for (int b = 0; b < 16; b++) {
      float h = hs[b * FD2 + row];
      a0[b] += wv.x * h;
      a1[b] += wv.y * h;
    }
  }
  float2* red2 = reinterpret_cast<float2*>(red);
  for (int ww = 0; ww < 4; ww++) {
    if (w == ww) {
#pragma unroll
      for (int b = 0; b < 16; b++) {
        if (ww == 0) {
          red2[b * 64 + lane] = make_float2(a0[b], a1[b]);
        } else {
          float2 r2 = red2[b * 64 + lane];
          r2.x += a0[b]; r2.y += a1[b];
          red2[b * 64 + lane] = r2;
        }
      }
    }
    __syncthreads();
  }
  for (int i = threadIdx.x; i < 2048; i += 256)
    part[(size_t)blockIdx.x * 2048 + i] = red[i];
}

// Stage 2: 8 blocks x 256 threads; each thread reduces 1250 partials + bias.
__global__ __launch_bounds__(256) void k_final2(const float* __restrict__ part, const float* __restrict__ bl,
                                                float* __restrict__ out) {
  int o = blockIdx.x * 256 + threadIdx.x;   // 0..2047
  float s = bl[o & 127];
#pragma unroll 10
  for (int p = 0; p < 1250; p++) s += part[(size_t)p * 2048 + o];
  out[o] = s;
}

// ----------------- launcher -----------------
extern "C" void kernel_launch(void* const* d_in, const int* in_sizes, int n_in,
                              void* d_out, int out_size, void* d_ws, size_t ws_size,
                              hipStream_t stream) {
  const float* x   = (const float*)d_in[0];
  const int*   ei  = (const int*)d_in[1];   // harness stages ALL integer inputs as int32
  const float* W0  = (const float*)d_in[2];
  const float* b0  = (const float*)d_in[3];
  const float* g0  = (const float*)d_in[4];
  const float* be0 = (const float*)d_in[5];
  const float* W1  = (const float*)d_in[6];
  const float* b1  = (const float*)d_in[7];
  const float* g1  = (const float*)d_in[8];
  const float* be1 = (const float*)d_in[9];
  const float* W2  = (const float*)d_in[10];
  const float* b2  = (const float*)d_in[11];
  const float* g2  = (const float*)d_in[12];
  const float* be2 = (const float*)d_in[13];
  const float* Wl  = (const float*)d_in[14];
  const float* bl  = (const float*)d_in[15];
  float* out = (float*)d_out;
  (void)in_sizes; (void)n_in; (void)out_size; (void)ws_size;

  char* pw = (char*)d_ws;
  auto carve = [&](size_t bytes) -> void* {
    void* r = (void*)pw;
    pw += (bytes + 255) & ~(size_t)255;
    return r;
  };
  int*            deg      = (int*)   carve((size_t)NN * 4);
  int*            cursor   = (int*)   carve((size_t)NN * 4);   // adjacent to deg (NN*4 % 256 == 0)
  int*            rowStart = (int*)   carve((size_t)(NN + 1) * 4);
  int*            bsum     = (int*)   carve(1024 * 4);
  float*          dis      = (float*) carve((size_t)NN * 4);
  int2*           ew       = (int2*)  carve((size_t)EE * 8);
  unsigned short* Cwt      = (unsigned short*)carve((size_t)384 * 128 * 2);
  unsigned short* TxAll    = (unsigned short*)carve((size_t)NN * 32 * 2);
  float*          A3       = (float*) carve((size_t)NN * 3 * 4);
  float*          B3       = (float*) carve((size_t)NN * 3 * 4);
  unsigned short* Hbuf     = (unsigned short*)carve((size_t)NN * 128 * 2);
  unsigned short* Ybuf     = (unsigned short*)carve((size_t)NN * 384 * 2);
  float*          part     = (float*) carve((size_t)1250 * 2048 * 4);

  // ---- CSR build ----
  k_zero<<<1250, 256, 0, stream>>>(deg, 2 * NN);   // deg + cursor in one pass
  k_hist<<<10000, 256, 0, stream>>>(ei, deg);
  k_dis<<<625, 256, 0, stream>>>(deg, dis);
  k_scan1<<<625, 256, 0, stream>>>(deg, rowStart, bsum);
  k_scan2<<<1, 1024, 0, stream>>>(bsum, 625);
  k_scan3<<<625, 256, 0, stream>>>(rowStart, bsum);
  k_scatter<<<10000, 256, 0, stream>>>(ei, rowStart, cursor, dis, ew);

  // ---- Layer 0 (3 -> 128): classic Chebyshev, TxAll (NN x 32 fp16, zero-pad) ----
  k_zero<<<10000, 256, 0, stream>>>((int*)TxAll, NN * 16);
  k_copyx<<<1875, 256, 0, stream>>>(x, A3, TxAll);
  k_prop3<1><<<625, 256, 0, stream>>>(A3, B3, TxAll, 1, rowStart, ew);
  k_prop3<2><<<625, 256, 0, stream>>>(B3, A3, TxAll, 2, rowStart, ew);
  k_prop3<2><<<625, 256, 0, stream>>>(A3, B3, TxAll, 3, rowStart, ew);
  k_prop3<2><<<625, 256, 0, stream>>>(B3, A3, TxAll, 4, rowStart, ew);
  k_prop3<2><<<625, 256, 0, stream>>>(A3, B3, TxAll, 5, rowStart, ew);
  k_padW0<<<16, 256, 0, stream>>>(W0, Cwt);
  k_gemm<32, 128><<<dim3(2500, 2), 256, 0, stream>>>(TxAll, Cwt, Ybuf);
  k_gn<16><<<5000, 256, 0, stream>>>(Ybuf, b0, g0, be0, Hbuf);

  // ---- Layer 1 (128 -> 64): one MFMA GEMM + 5 Horner props in cout space ----
  k_combine<128, 64><<<192, 256, 0, stream>>>(W1, Cwt);
  k_gemm<128, 64><<<dim3(2500, 6), 256, 0, stream>>>(Hbuf, Cwt, Ybuf);
  for (int j = 4; j >= 0; j--)
    k_horner<32><<<20000, 256, 0, stream>>>((unsigned*)(Ybuf + (size_t)(j + 1) * NN * 64),
                                            (unsigned*)(Ybuf + (size_t)j * NN * 64), rowStart, ew);
  k_gn<8><<<5000, 256, 0, stream>>>(Ybuf, b1, g1, be1, Hbuf);

  // ---- Layer 2 (64 -> 32) ----
  k_combine<64, 32><<<48, 256, 0, stream>>>(W2, Cwt);
  k_gemm<64, 32><<<dim3(2500, 3), 256, 0, stream>>>(Hbuf, Cwt, Ybuf);
  for (int j = 4; j >= 0; j--)
    k_horner<16><<<10000, 256, 0, stream>>>((unsigned*)(Ybuf + (size_t)(j + 1) * NN * 32),
                                            (unsigned*)(Ybuf + (size_t)j * NN * 32), rowStart, ew);
  k_gn<4><<<5000, 256, 0, stream>>>(Ybuf, b2, g2, be2, Hbuf);

  // ---- Readout: 2-stage split-K ----
  k_final1<<<1250, 256, 0, stream>>>(Hbuf, Wl, part);
  k_final2<<<8, 256, 0, stream>>>(part, bl, out);
}